// Round 15
// baseline (1701.266 us; speedup 1.0000x reference)
//
#include <hip/hip_runtime.h>
#include <cstdint>
#include <cstddef>

#define BB 8
#define NN 8192
#define SS 2048
#define KNB 32
#define NTASKS (BB * (SS / 16))
#define NBLOCKS 96   // 8 producers + 88 consumers (R15: was 256; only ~14
                     // consumers are ever busy at once — fewer spinning CUs
                     // => higher boost clock for the serial-critical producers)

typedef float f32x2 __attribute__((ext_vector_type(2)));

// Bit-exact squared distance matching numpy: (a-b) per component, squares,
// left-to-right sum, no FMA contraction.
__device__ __forceinline__ float sqdist_exact(float ax, float ay, float az,
                                              float bx, float by, float bz) {
#pragma clang fp contract(off)
    float dx = ax - bx;
    float dy = ay - by;
    float dz = az - bz;
    return (dx * dx + dy * dy) + dz * dz;
}

// Packed 2-wide exact sqdist: same op order per component, no contraction.
__device__ __forceinline__ f32x2 sqdist2_exact(f32x2 px, f32x2 py, f32x2 pz,
                                               f32x2 cx2, f32x2 cy2, f32x2 cz2) {
#pragma clang fp contract(off)
    f32x2 dx = px - cx2;
    f32x2 dy = py - cy2;
    f32x2 dz = pz - cz2;
    return (dx * dx + dy * dy) + dz * dz;
}

// u64 max (compare-select, branchless)
__device__ __forceinline__ unsigned long long u64max(unsigned long long a,
                                                     unsigned long long b) {
    return (a > b) ? a : b;
}

// DPP u64 max step (row_shr/row_bcast legal on CDNA4). Identity 0 safe.
template <int CTRL>
__device__ __forceinline__ unsigned long long dpp_u64max_step(unsigned long long k) {
    int lo = __builtin_amdgcn_update_dpp(0, (int)(unsigned)(k & 0xffffffffu),
                                         CTRL, 0xf, 0xf, false);
    int hi = __builtin_amdgcn_update_dpp(0, (int)(unsigned)(k >> 32),
                                         CTRL, 0xf, 0xf, false);
    unsigned long long o = ((unsigned long long)(unsigned)hi << 32) | (unsigned)lo;
    return (o > k) ? o : k;
}
#define ROW_SHR1 0x111
#define ROW_SHR2 0x112
#define ROW_SHR4 0x114
#define ROW_SHR8 0x118
#define ROW_BC15 0x142
#define ROW_BC31 0x143

// full-wave min/max butterfly (init-time only)
__device__ __forceinline__ void wave_minmax(float x, float& lo, float& hi) {
    float a = x, b = x;
#pragma unroll
    for (int off = 1; off < 64; off <<= 1) {
        a = fminf(a, __shfl_xor(a, off));
        b = fmaxf(b, __shfl_xor(b, off));
    }
    lo = a;
    hi = b;
}

// ---------------------------------------------------------------------------
// Weight transpose prep + zero the producer/consumer sync area (runs at the
// head of every launch/replay, so re-runs are self-initializing).
// syncWs layout: prog[b] at syncWs[b*32] (128B apart, one line per batch);
// taskCtr at syncWs[256].
// ---------------------------------------------------------------------------
__global__ void prep_kernel(const float* __restrict__ w1, const float* __restrict__ w2,
                            const float* __restrict__ w3, float* __restrict__ w1T,
                            float* __restrict__ w2T, float* __restrict__ w3T,
                            int* __restrict__ syncWs) {
    for (int i = threadIdx.x; i < 288; i += 256) syncWs[i] = 0;
    for (int i = threadIdx.x; i < 192; i += 256) {
        int oc = i / 3, c = i % 3;
        w1T[c * 64 + oc] = w1[i];
    }
    for (int i = threadIdx.x; i < 4096; i += 256) {
        int oc = i >> 6, j = i & 63;
        w2T[j * 64 + oc] = w2[i];
    }
    for (int i = threadIdx.x; i < 8192; i += 256) {
        int oc = i >> 6, j = i & 63;
        w3T[j * 128 + oc] = w3[i];
    }
}

// spread 3-bit value to bit positions 0,3,6
__device__ __forceinline__ int part3(int v) {
    return (v & 1) | ((v & 2) << 2) | ((v & 4) << 4);
}

#define P4_LIST(X) X(0) X(1) X(2) X(3)

// ---------------------------------------------------------------------------
// Consumer loop (verified R14): publish-ordered task mapping (bb = t&7),
// relaxed agent-scope polling on padded prog lines, acquire threadfence
// before data reads. Block = 1024 threads = 8 sub-blocks of 128.
// ---------------------------------------------------------------------------
__device__ __forceinline__ void consume_tasks(
    char* smemRaw, int* taskS, const float* __restrict__ xyz_all,
    const float4* __restrict__ wsCtr, const float* __restrict__ w1T,
    const float* __restrict__ b1, const float* __restrict__ w2T,
    const float* __restrict__ b2, const float* __restrict__ w3T,
    const float* __restrict__ b3, float* __restrict__ out1,
    int* __restrict__ prog, int* __restrict__ taskCtr) {
    const int tid = threadIdx.x;
    const int l = tid & 63;
    const int sub = tid >> 7;                                   // 0..7
    const int cb = __builtin_amdgcn_readfirstlane((tid >> 6) & 1);
    float* hT = ((float*)smemRaw) + sub * 4096;                 // [64 ch][64 rows]
    float* relF = ((float*)smemRaw) + 8 * 4096 + sub * 192;     // [64 rows][3]

    for (;;) {
        if (tid == 0) *taskS = atomicAdd(taskCtr, 1);
        __syncthreads();
        const int t = *taskS;
        if (t >= NTASKS) break;
        const int bb = t & 7;                 // publish-ordered mapping
        const int base = (t >> 3) << 4;
        if (tid == 0) {
            while (__hip_atomic_load(&prog[bb * 32], __ATOMIC_RELAXED,
                                     __HIP_MEMORY_SCOPE_AGENT) < base + 16)
                __builtin_amdgcn_s_sleep(64);
        }
        __syncthreads();
        __threadfence();  // acquire: invalidate stale lines before reading ctr
        const int s0 = base + sub * 2;
        const float* xyz = xyz_all + (size_t)bb * NN * 3;

        // ---- ball query: wave cb of this sub handles center s0+cb
        {
            float4 cc = wsCtr[(size_t)bb * SS + s0 + cb];
            float ccx = cc.x, ccy = cc.y, ccz = cc.z;
            const float R2 = (float)(0.2 * 0.2);
            int total = 0;
            float fx = 0.f, fy = 0.f, fz = 0.f;
            bool have = false;
            for (int chunk = 0; chunk < 128 && total < KNB; ++chunk) {
                int p = chunk * 64 + l;
                float x = xyz[p * 3 + 0], y = xyz[p * 3 + 1], z = xyz[p * 3 + 2];
                float d = sqdist_exact(ccx, ccy, ccz, x, y, z);
                bool hit = (d <= R2);
                unsigned long long mask = __ballot(hit);
                int cnt = __popcll(mask);
                if (cnt) {
                    int pos = total + __popcll(mask & ((1ull << l) - 1ull));
                    float rx = x - ccx, ry = y - ccy, rz = z - ccz;
                    if (hit && pos < KNB) {
                        relF[(cb * KNB + pos) * 3 + 0] = rx;
                        relF[(cb * KNB + pos) * 3 + 1] = ry;
                        relF[(cb * KNB + pos) * 3 + 2] = rz;
                    }
                    if (hit && pos == 0) { fx = rx; fy = ry; fz = rz; have = true; }
                    total += cnt;
                }
            }
            unsigned long long hm = __ballot(have);
            if (total < KNB) {
                int src = __ffsll((long long)hm) - 1;
                float gx = __shfl(fx, src), gy = __shfl(fy, src), gz = __shfl(fz, src);
                if (l >= total && l < KNB) {
                    relF[(cb * KNB + l) * 3 + 0] = gx;
                    relF[(cb * KNB + l) * 3 + 1] = gy;
                    relF[(cb * KNB + l) * 3 + 2] = gz;
                }
            }
        }
        __syncthreads();

        const int r = l;  // rows 0..31 center s0, rows 32..63 center s0+1

        // ---- layer 1: rel(3) -> 64
        {
            float rx = relF[r * 3 + 0], ry = relF[r * 3 + 1], rz = relF[r * 3 + 2];
#pragma unroll
            for (int i = 0; i < 32; ++i) {
                int ch = cb * 32 + i;
                float h = b1[ch];
                h = fmaf(rx, w1T[0 * 64 + ch], h);
                h = fmaf(ry, w1T[1 * 64 + ch], h);
                h = fmaf(rz, w1T[2 * 64 + ch], h);
                hT[ch * 64 + r] = fmaxf(h, 0.0f);
            }
        }
        __syncthreads();

        // ---- layer 2: 64 -> 64 (h2 overwrites h1 in place after barrier)
        {
            float acc[32];
#pragma unroll
            for (int i = 0; i < 32; ++i) acc[i] = b2[cb * 32 + i];
#pragma unroll 2
            for (int j = 0; j < 64; ++j) {
                float a = hT[j * 64 + r];
                const float4* wrow = (const float4*)(w2T + j * 64 + cb * 32);
#pragma unroll
                for (int i4 = 0; i4 < 8; ++i4) {
                    float4 w = wrow[i4];
                    acc[i4 * 4 + 0] = fmaf(a, w.x, acc[i4 * 4 + 0]);
                    acc[i4 * 4 + 1] = fmaf(a, w.y, acc[i4 * 4 + 1]);
                    acc[i4 * 4 + 2] = fmaf(a, w.z, acc[i4 * 4 + 2]);
                    acc[i4 * 4 + 3] = fmaf(a, w.w, acc[i4 * 4 + 3]);
                }
            }
            __syncthreads();
#pragma unroll
            for (int i = 0; i < 32; ++i) hT[(cb * 32 + i) * 64 + r] = fmaxf(acc[i], 0.0f);
        }
        __syncthreads();

        // ---- layer 3: 64 -> 128 in two 32-channel halves + maxpool + store
#pragma unroll 1
        for (int half = 0; half < 2; ++half) {
            float acc[32];
#pragma unroll
            for (int i = 0; i < 32; ++i) acc[i] = b3[cb * 64 + half * 32 + i];
#pragma unroll 2
            for (int j = 0; j < 64; ++j) {
                float a = hT[j * 64 + r];
                const float4* wrow = (const float4*)(w3T + j * 128 + cb * 64 + half * 32);
#pragma unroll
                for (int i4 = 0; i4 < 8; ++i4) {
                    float4 w = wrow[i4];
                    acc[i4 * 4 + 0] = fmaf(a, w.x, acc[i4 * 4 + 0]);
                    acc[i4 * 4 + 1] = fmaf(a, w.y, acc[i4 * 4 + 1]);
                    acc[i4 * 4 + 2] = fmaf(a, w.z, acc[i4 * 4 + 2]);
                    acc[i4 * 4 + 3] = fmaf(a, w.w, acc[i4 * 4 + 3]);
                }
            }
#pragma unroll
            for (int i = 0; i < 32; ++i) {
                float v = fmaxf(acc[i], 0.0f);
                v = fmaxf(v, __shfl_xor(v, 1));
                v = fmaxf(v, __shfl_xor(v, 2));
                v = fmaxf(v, __shfl_xor(v, 4));
                v = fmaxf(v, __shfl_xor(v, 8));
                v = fmaxf(v, __shfl_xor(v, 16));
                acc[i] = v;
            }
            if ((l & 31) == 0) {
                int sA = s0 + (l >> 5);
                float* op = out1 + ((size_t)bb * 128 + cb * 64 + half * 32) * SS + sA;
#pragma unroll
                for (int i = 0; i < 32; ++i) op[(size_t)i * SS] = acc[i];
            }
        }
        __syncthreads();  // protect relF/hT before next task
    }
}

// ---------------------------------------------------------------------------
// Fused producer-consumer kernel (verified R14 structure). R15: grid 96.
// Blocks 0..7: R19 FPS + epoch-lagged publish (fence waits only epoch-old
// stores; chunk-k ctr stores issued after the exch that publishes chunk k-1).
// Blocks 8..95: consumers. Producers fall into the consumer loop when done,
// so completion never depends on scheduling.
// ---------------------------------------------------------------------------
__global__ __attribute__((amdgpu_flat_work_group_size(1024, 1024)))
void fused_kernel(const float* __restrict__ xyz_all,
                  float4* __restrict__ wsSorted,
                  float4* __restrict__ wsCtr,
                  float* __restrict__ out0,
                  const float* __restrict__ w1T, const float* __restrict__ b1,
                  const float* __restrict__ w2T, const float* __restrict__ b2,
                  const float* __restrict__ w3T, const float* __restrict__ b3,
                  float* __restrict__ out1, int* __restrict__ syncWs) {
    __shared__ __align__(16) char smemRaw[137216];
    __shared__ int taskS;
    int* prog = syncWs;           // prog[b] at syncWs[b*32]
    int* taskCtr = syncWs + 256;

    const int tid = threadIdx.x;
    const int wid = tid >> 6;
    const int lane = tid & 63;

    if (blockIdx.x < BB) {
        // ================= producer: FPS for batch b =================
        const int b = blockIdx.x;
        const float* xyz = xyz_all + (size_t)b * NN * 3;
        float4* sorted = wsSorted + (size_t)b * NN;
        float4* ctr = wsCtr + (size_t)b * SS;
        float* o0 = out0 + (size_t)b * 3 * SS;

        float* xLds = (float*)smemRaw;                 // NN
        float* yLds = xLds + NN;
        float* zLds = yLds + NN;
        float4* ctrLds = (float4*)(zLds + NN);         // SS
        int* cellCnt = (int*)(ctrLds + SS);            // 512
        int* cellBase = cellCnt + 512;                 // 512
        unsigned long long* redp = (unsigned long long*)(cellBase + 512);  // [2*16]

        // --- pass 1: Morton-cell counts (8 pts/thread) + stage xyz in LDS
        if (tid < 512) cellCnt[tid] = 0;
        __syncthreads();
        int cellReg[8];
#pragma unroll
        for (int j = 0; j < 8; ++j) {
            int p = tid + j * 1024;
            float x = xyz[p * 3 + 0], y = xyz[p * 3 + 1], z = xyz[p * 3 + 2];
            xLds[p] = x; yLds[p] = y; zLds[p] = z;
            int qx = min(7, (int)(x * 8.0f));
            int qy = min(7, (int)(y * 8.0f));
            int qz = min(7, (int)(z * 8.0f));
            cellReg[j] = part3(qx) | (part3(qy) << 1) | (part3(qz) << 2);
            atomicAdd(&cellCnt[cellReg[j]], 1);
        }
        __syncthreads();
        int myCnt = (tid < 512) ? cellCnt[tid] : 0;
        for (int off = 1; off < 512; off <<= 1) {
            int v = (tid < 512 && tid >= off) ? cellCnt[tid - off] : 0;
            __syncthreads();
            if (tid < 512) cellCnt[tid] += v;
            __syncthreads();
        }
        if (tid < 512) cellBase[tid] = cellCnt[tid] - myCnt;
        __syncthreads();
        // --- pass 2: scatter to global ws in Morton order
#pragma unroll
        for (int j = 0; j < 8; ++j) {
            int p = tid + j * 1024;
            float x = xLds[p], y = yLds[p], z = zLds[p];
            int pos = atomicAdd(&cellBase[cellReg[j]], 1);
            sorted[pos] = make_float4(x, y, z, __int_as_float(p));
        }
        __threadfence();
        __syncthreads();

        // --- 8 bricks as 4 packed pairs
#define DECL_PR(j)                                                   \
        f32x2 px##j, py##j, pz##j, dist##j;                          \
        int ndA##j, ndB##j;                                          \
        {                                                            \
            float4 va = sorted[(wid * 8 + 2 * j) * 64 + lane];       \
            float4 vb = sorted[(wid * 8 + 2 * j + 1) * 64 + lane];   \
            px##j = (f32x2){va.x, vb.x};                             \
            py##j = (f32x2){va.y, vb.y};                             \
            pz##j = (f32x2){va.z, vb.z};                             \
            ndA##j = ~__float_as_int(va.w);                          \
            ndB##j = ~__float_as_int(vb.w);                          \
            dist##j = (f32x2){1e10f, 1e10f};                         \
        }
        P4_LIST(DECL_PR)

        float bbxlo = 0.f, bbxhi = 0.f, bbylo = 0.f, bbyhi = 0.f,
              bbzlo = 0.f, bbzhi = 0.f;
#define BRICK_BB2(j)                                              \
        {                                                         \
            float xl, xh, yl, yh, zl, zh;                         \
            wave_minmax(px##j.x, xl, xh);                         \
            wave_minmax(py##j.x, yl, yh);                         \
            wave_minmax(pz##j.x, zl, zh);                         \
            if (lane == 2 * j) {                                  \
                bbxlo = xl; bbxhi = xh;                           \
                bbylo = yl; bbyhi = yh;                           \
                bbzlo = zl; bbzhi = zh;                           \
            }                                                     \
            wave_minmax(px##j.y, xl, xh);                         \
            wave_minmax(py##j.y, yl, yh);                         \
            wave_minmax(pz##j.y, zl, zh);                         \
            if (lane == 2 * j + 1) {                              \
                bbxlo = xl; bbxhi = xh;                           \
                bbylo = yl; bbyhi = yh;                           \
                bbzlo = zl; bbzhi = zh;                           \
            }                                                     \
        }
        P4_LIST(BRICK_BB2)

        float cx = xLds[0], cy = yLds[0], cz = zLds[0];
        if (tid == 0) ctrLds[0] = make_float4(cx, cy, cz, 0.0f);

        unsigned long long waveKey =
            ((unsigned long long)__float_as_uint(1e10f) << 32) | 0xFFFFFFFFull;
        float wave_bv = 1e10f;

        for (int s = 1; s < SS; ++s) {
            const int par = s & 1;
            float ddx = fmaxf(fmaxf(bbxlo - cx, cx - bbxhi), 0.0f);
            float ddy = fmaxf(fmaxf(bbylo - cy, cy - bbyhi), 0.0f);
            float ddz = fmaxf(fmaxf(bbzlo - cz, cz - bbzhi), 0.0f);
            float lb2 = (ddx * ddx + ddy * ddy) + ddz * ddz;
            bool act = (lane < 8) && (lb2 * 0.999f < wave_bv);
            if (__ballot(act)) {
                const f32x2 c2x = (f32x2){cx, cx};
                const f32x2 c2y = (f32x2){cy, cy};
                const f32x2 c2z = (f32x2){cz, cz};
#define UPD_PR(j)                                                        \
                {                                                        \
                    f32x2 d = sqdist2_exact(px##j, py##j, pz##j, c2x, c2y, c2z); \
                    dist##j.x = fminf(dist##j.x, d.x);                   \
                    dist##j.y = fminf(dist##j.y, d.y);                   \
                }
                P4_LIST(UPD_PR)
#define KEY_PR(j)                                                        \
                unsigned long long kA##j =                               \
                    ((unsigned long long)__float_as_uint(dist##j.x) << 32) | \
                    (unsigned)ndA##j;                                    \
                unsigned long long kB##j =                               \
                    ((unsigned long long)__float_as_uint(dist##j.y) << 32) | \
                    (unsigned)ndB##j;
                P4_LIST(KEY_PR)
                unsigned long long t0 = u64max(kA0, kB0), t1 = u64max(kA1, kB1),
                                   t2 = u64max(kA2, kB2), t3 = u64max(kA3, kB3);
                unsigned long long K = u64max(u64max(t0, t1), u64max(t2, t3));
                K = dpp_u64max_step<ROW_SHR1>(K);
                K = dpp_u64max_step<ROW_SHR2>(K);
                K = dpp_u64max_step<ROW_SHR4>(K);
                K = dpp_u64max_step<ROW_SHR8>(K);
                K = dpp_u64max_step<ROW_BC15>(K);
                K = dpp_u64max_step<ROW_BC31>(K);
                if (lane == 63) redp[par * 16 + wid] = K;
                unsigned wlo = (unsigned)__builtin_amdgcn_readlane(
                    (int)(unsigned)(K & 0xffffffffu), 63);
                unsigned whi = (unsigned)__builtin_amdgcn_readlane(
                    (int)(unsigned)(K >> 32), 63);
                waveKey = ((unsigned long long)whi << 32) | wlo;
                wave_bv = __int_as_float((int)whi);
            } else {
                if (lane == 0) redp[par * 16 + wid] = waveKey;
            }
            __syncthreads();
            unsigned long long k = redp[par * 16 + (lane & 15)];
            k = dpp_u64max_step<ROW_SHR1>(k);
            k = dpp_u64max_step<ROW_SHR2>(k);
            k = dpp_u64max_step<ROW_SHR4>(k);
            k = dpp_u64max_step<ROW_SHR8>(k);
            unsigned blo = (unsigned)__builtin_amdgcn_readlane(
                (int)(unsigned)(k & 0xffffffffu), 15);
            int wiu = (int)(~blo);
            cx = xLds[wiu];
            cy = yLds[wiu];
            cz = zLds[wiu];
            if (tid == 0) ctrLds[s] = make_float4(cx, cy, cz, 0.0f);
            if ((s & 15) == 15 && wid == 0) {
                // epoch-lagged publish: fence waits only epoch-old stores
                __threadfence();
                if (lane == 0) atomicExch(&prog[b * 32], s - 15);
                int cs = s - 15 + lane;
                if (lane < 16) ctr[cs] = ctrLds[cs];  // issue chunk-k stores
            }
        }

        // final publish: last chunk's stores fenced, then full count
        if (wid == 0) {
            __threadfence();
            if (lane == 0) atomicExch(&prog[b * 32], SS);
        }

        // --- write new_xyz output (centers already in wsCtr)
        __syncthreads();
        for (int s = tid; s < SS; s += 1024) {
            float4 c = ctrLds[s];
            o0[s] = c.x;
            o0[SS + s] = c.y;
            o0[2 * SS + s] = c.z;
        }
        // help drain remaining consumer tasks (also guarantees completion
        // regardless of block scheduling)
        consume_tasks(smemRaw, &taskS, xyz_all, wsCtr, w1T, b1, w2T, b2,
                      w3T, b3, out1, prog, taskCtr);
    } else {
        // ================= consumer =================
        consume_tasks(smemRaw, &taskS, xyz_all, wsCtr, w1T, b1, w2T, b2,
                      w3T, b3, out1, prog, taskCtr);
    }
}

extern "C" void kernel_launch(void* const* d_in, const int* in_sizes, int n_in,
                              void* d_out, int out_size, void* d_ws, size_t ws_size,
                              hipStream_t stream) {
    (void)in_sizes; (void)n_in; (void)out_size; (void)ws_size;
    const float* xyz = (const float*)d_in[0];
    // d_in[1] = features : unused by the reference
    const float* w1 = (const float*)d_in[2];
    const float* b1 = (const float*)d_in[3];
    const float* w2 = (const float*)d_in[4];
    const float* b2 = (const float*)d_in[5];
    const float* w3 = (const float*)d_in[6];
    const float* b3 = (const float*)d_in[7];
    float* out = (float*)d_out;

    // workspace layout
    float4* wsCtr = (float4*)d_ws;              // B*S float4      (256 KB)
    float4* wsSorted = wsCtr + BB * SS;         // B*N float4      (1 MB)
    float* w1T = (float*)(wsSorted + BB * NN);  // 192 f
    float* w2T = w1T + 192;                     // 4096 f
    float* w3T = w2T + 4096;                    // 8192 f
    int* syncWs = (int*)(w3T + 8192);           // 288 ints (padded prog + taskCtr)

    prep_kernel<<<1, 256, 0, stream>>>(w1, w2, w3, w1T, w2T, w3T, syncWs);
    fused_kernel<<<NBLOCKS, 1024, 0, stream>>>(xyz, wsSorted, wsCtr, out,
                                               w1T, b1, w2T, b2, w3T, b3,
                                               out + BB * 3 * SS, syncWs);
}